// Round 1
// baseline (511.346 us; speedup 1.0000x reference)
//
#include <hip/hip_runtime.h>
#include <cmath>

typedef __bf16 bf16;
typedef __attribute__((ext_vector_type(8))) __bf16 bf16x8;
typedef __attribute__((ext_vector_type(4))) __bf16 bf16x4;
typedef __attribute__((ext_vector_type(4))) float f32x4;

#define DEVINL __device__ __forceinline__

DEVINL void gload16(const void* g, void* l) {
    __builtin_amdgcn_global_load_lds((const __attribute__((address_space(1))) void*)g,
                                     (__attribute__((address_space(3))) void*)l, 16, 0, 0);
}

// ---------------- utility kernels ----------------

__global__ void cast_bf16_kernel(const float* __restrict__ in, bf16* __restrict__ out, int n4) {
    int i = blockIdx.x * 256 + threadIdx.x;
    if (i < n4) {
        float4 v = ((const float4*)in)[i];
        bf16x4 o;
        o[0] = (bf16)v.x; o[1] = (bf16)v.y; o[2] = (bf16)v.z; o[3] = (bf16)v.w;
        ((bf16x4*)out)[i] = o;
    }
}

// in: [R][C] f32  ->  out: [C][R] bf16
__global__ void tcast_kernel(const float* __restrict__ in, bf16* __restrict__ out, int R, int C) {
    __shared__ float t[32][33];
    int tx = threadIdx.x & 31, ty = threadIdx.x >> 5;
    int r0 = blockIdx.y * 32, c0 = blockIdx.x * 32;
#pragma unroll
    for (int i = 0; i < 4; ++i)
        t[ty + 8 * i][tx] = in[(size_t)(r0 + ty + 8 * i) * C + c0 + tx];
    __syncthreads();
#pragma unroll
    for (int i = 0; i < 4; ++i)
        out[(size_t)(c0 + ty + 8 * i) * R + r0 + tx] = (bf16)t[tx][ty + 8 * i];
}

__global__ void concat_bias_kernel(const float* __restrict__ a, const float* __restrict__ b,
                                   const float* __restrict__ c, float* __restrict__ out) {
    int i = blockIdx.x * 256 + threadIdx.x;
    if (i < 2304) out[i] = (i < 768) ? a[i] : ((i < 1536) ? b[i - 768] : c[i - 1536]);
}

// ---------------- GEMM: C[M][N] = A[M][K] * Bt[N][K]^T + bias ----------------
// MODE 0: store bf16; MODE 1: store f32; MODE 2: gelu, store bf16
template<int MODE>
__global__ void gemm_kernel(const bf16* __restrict__ A, const bf16* __restrict__ Bt,
                            const float* __restrict__ bias,
                            bf16* __restrict__ Cb, float* __restrict__ Cf,
                            int M, int N, int K, int ldc) {
    __shared__ __align__(16) bf16 As[128 * 64];
    __shared__ __align__(16) bf16 Bs[128 * 64];
    const int tid = threadIdx.x;
    const int wid = tid >> 6, lane = tid & 63;
    const int m0 = blockIdx.y * 128, n0 = blockIdx.x * 128;
    const int wr = (wid >> 1) * 64, wc = (wid & 1) * 64;
    const int lg = lane >> 4, l15 = lane & 15;
    f32x4 acc[4][4] = {};

    for (int k0 = 0; k0 < K; k0 += 64) {
        __syncthreads();
#pragma unroll
        for (int i = 0; i < 4; ++i) {
            const int cbase = (wid * 4 + i) * 1024;
            const int td = cbase + lane * 16;
            const int row = td >> 7;                         // 128 B per tile row
            const int s16 = ((td >> 4) & 7) ^ (row & 7);     // pre-swizzled source slot
            gload16(A + (size_t)(m0 + row) * K + k0 + s16 * 8, (char*)As + cbase);
            gload16(Bt + (size_t)(n0 + row) * K + k0 + s16 * 8, (char*)Bs + cbase);
        }
        __syncthreads();
#pragma unroll
        for (int kk = 0; kk < 2; ++kk) {
            bf16x8 af[4], bfr[4];
#pragma unroll
            for (int mi = 0; mi < 4; ++mi) {
                int ra = wr + mi * 16 + l15;
                int off = (ra * 128 + (kk * 32 + 8 * lg) * 2) ^ ((ra & 7) << 4);
                af[mi] = *(const bf16x8*)((const char*)As + off);
            }
#pragma unroll
            for (int ni = 0; ni < 4; ++ni) {
                int rb = wc + ni * 16 + l15;
                int off = (rb * 128 + (kk * 32 + 8 * lg) * 2) ^ ((rb & 7) << 4);
                bfr[ni] = *(const bf16x8*)((const char*)Bs + off);
            }
#pragma unroll
            for (int mi = 0; mi < 4; ++mi)
#pragma unroll
                for (int ni = 0; ni < 4; ++ni)
                    acc[mi][ni] = __builtin_amdgcn_mfma_f32_16x16x32_bf16(af[mi], bfr[ni], acc[mi][ni], 0, 0, 0);
        }
    }
#pragma unroll
    for (int mi = 0; mi < 4; ++mi) {
#pragma unroll
        for (int r = 0; r < 4; ++r) {
            const int row = m0 + wr + mi * 16 + lg * 4 + r;
#pragma unroll
            for (int ni = 0; ni < 4; ++ni) {
                const int col = n0 + wc + ni * 16 + l15;
                float v = acc[mi][ni][r] + bias[col];
                if (MODE == 2) v = v * 0.5f * (1.0f + erff(v * 0.70710678118654752f));
                if (MODE == 1) Cf[(size_t)row * ldc + col] = v;
                else           Cb[(size_t)row * ldc + col] = (bf16)v;
            }
        }
    }
}

// ---------------- attention ----------------
// qkv: [8192][2304] bf16 (Q|K|V each 768 = 12 heads * 64)
// pb:  [12][1024][1024] f32 ; mask: [8][1024][1024] f32 ; ctx: [8192][768] bf16
__global__ __launch_bounds__(256) void attn_kernel(const bf16* __restrict__ qkv,
                                                   const float* __restrict__ pb,
                                                   const float* __restrict__ mask,
                                                   bf16* __restrict__ ctx) {
    __shared__ __align__(16) bf16 probs[16 * 1032];
    __shared__ __align__(16) bf16 Vt[64 * 136];
    __shared__ float redA[4][16];
    __shared__ float redB[4][16];
    const int tid = threadIdx.x, wid = tid >> 6, lane = tid & 63;
    const int b = blockIdx.y / 12, h = blockIdx.y % 12;
    const int q0 = blockIdx.x * 16;
    const int lg = lane >> 4, l15 = lane & 15;

    const size_t rowQ = (size_t)(b * 1024 + q0 + l15) * 2304 + h * 64 + 8 * lg;
    bf16x8 aq0 = *(const bf16x8*)(qkv + rowQ);
    bf16x8 aq1 = *(const bf16x8*)(qkv + rowQ + 32);

    f32x4 sc[16];
    const size_t pbb = ((size_t)h * 1024 + q0) * 1024;
    const size_t mkb = ((size_t)b * 1024 + q0) * 1024;
#pragma unroll
    for (int t = 0; t < 16; ++t) {
        const int n0 = wid * 256 + t * 16;
        const size_t rowK = (size_t)(b * 1024 + n0 + l15) * 2304 + 768 + h * 64 + 8 * lg;
        bf16x8 bk0 = *(const bf16x8*)(qkv + rowK);
        bf16x8 bk1 = *(const bf16x8*)(qkv + rowK + 32);
        f32x4 s = {};
        s = __builtin_amdgcn_mfma_f32_16x16x32_bf16(aq0, bk0, s, 0, 0, 0);
        s = __builtin_amdgcn_mfma_f32_16x16x32_bf16(aq1, bk1, s, 0, 0, 0);
        const int nn = n0 + l15;
#pragma unroll
        for (int r = 0; r < 4; ++r) {
            const int m = lg * 4 + r;
            sc[t][r] = (s[r] + pb[pbb + (size_t)m * 1024 + nn]) * 0.125f
                     + mask[mkb + (size_t)m * 1024 + nn];
        }
    }
    // row max (16 lanes of same group hold the row's 16-col strips across t)
    float pm[4];
#pragma unroll
    for (int r = 0; r < 4; ++r) {
        float m = sc[0][r];
#pragma unroll
        for (int t = 1; t < 16; ++t) m = fmaxf(m, sc[t][r]);
#pragma unroll
        for (int off = 1; off <= 8; off <<= 1) m = fmaxf(m, __shfl_xor(m, off));
        pm[r] = m;
    }
    if (l15 == 0) {
#pragma unroll
        for (int r = 0; r < 4; ++r) redA[wid][lg * 4 + r] = pm[r];
    }
    __syncthreads();
    float gm[4], psum[4];
#pragma unroll
    for (int r = 0; r < 4; ++r) {
        const int m = lg * 4 + r;
        gm[r] = fmaxf(fmaxf(redA[0][m], redA[1][m]), fmaxf(redA[2][m], redA[3][m]));
        psum[r] = 0.f;
    }
#pragma unroll
    for (int t = 0; t < 16; ++t)
#pragma unroll
        for (int r = 0; r < 4; ++r) {
            float p = __expf(sc[t][r] - gm[r]);
            sc[t][r] = p;
            psum[r] += p;
        }
#pragma unroll
    for (int r = 0; r < 4; ++r) {
        float s = psum[r];
#pragma unroll
        for (int off = 1; off <= 8; off <<= 1) s += __shfl_xor(s, off);
        psum[r] = s;
    }
    if (l15 == 0) {
#pragma unroll
        for (int r = 0; r < 4; ++r) redB[wid][lg * 4 + r] = psum[r];
    }
    __syncthreads();
    float inv[4];
#pragma unroll
    for (int r = 0; r < 4; ++r) {
        const int m = lg * 4 + r;
        inv[r] = 1.0f / (redB[0][m] + redB[1][m] + redB[2][m] + redB[3][m]);
    }
#pragma unroll
    for (int t = 0; t < 16; ++t) {
        const int nn = wid * 256 + t * 16 + l15;
#pragma unroll
        for (int r = 0; r < 4; ++r)
            probs[(lg * 4 + r) * 1032 + nn] = (bf16)(sc[t][r] * inv[r]);
    }
    // PV: ctx[16][64] = P[16][1024] @ V[1024][64]; wave wid owns d-tile wid*16
    f32x4 cacc = {};
    const int d0 = wid * 16;
    for (int c = 0; c < 8; ++c) {
        __syncthreads();
#pragma unroll
        for (int i = 0; i < 4; ++i) {
            const int task = tid + 256 * i;
            const int r = task >> 3, gcol = task & 7;
            bf16x8 vv = *(const bf16x8*)(qkv + (size_t)(b * 1024 + c * 128 + r) * 2304 + 1536 + h * 64 + gcol * 8);
#pragma unroll
            for (int jj = 0; jj < 8; ++jj)
                Vt[(gcol * 8 + jj) * 136 + r] = vv[jj];
        }
        __syncthreads();
#pragma unroll
        for (int kc = 0; kc < 4; ++kc) {
            bf16x8 pa = *(const bf16x8*)(probs + l15 * 1032 + c * 128 + kc * 32 + 8 * lg);
            bf16x8 vb = *(const bf16x8*)(Vt + (d0 + l15) * 136 + kc * 32 + 8 * lg);
            cacc = __builtin_amdgcn_mfma_f32_16x16x32_bf16(pa, vb, cacc, 0, 0, 0);
        }
    }
#pragma unroll
    for (int r = 0; r < 4; ++r) {
        const int m = lg * 4 + r;
        ctx[(size_t)(b * 1024 + q0 + m) * 768 + h * 64 + d0 + l15] = (bf16)cacc[r];
    }
}

// ---------------- layernorm (one wave per row of 768) ----------------
// MODE 0: write f32 + bf16 ; MODE 1: write f32 only
template<int MODE>
__global__ __launch_bounds__(256) void ln_kernel(const float* __restrict__ x, const float* __restrict__ res,
                                                 const float* __restrict__ g, const float* __restrict__ bt,
                                                 float* __restrict__ outf, bf16* __restrict__ outb) {
    const int wid = threadIdx.x >> 6, lane = threadIdx.x & 63;
    const int row = blockIdx.x * 4 + wid;
    const float4* xr = (const float4*)(x + (size_t)row * 768);
    const float4* rr = (const float4*)(res + (size_t)row * 768);
    float4 v[3];
    float s = 0.f, ss = 0.f;
#pragma unroll
    for (int j = 0; j < 3; ++j) {
        float4 a = xr[lane + 64 * j];
        float4 b = rr[lane + 64 * j];
        float4 w;
        w.x = a.x + b.x; w.y = a.y + b.y; w.z = a.z + b.z; w.w = a.w + b.w;
        v[j] = w;
        s += w.x + w.y + w.z + w.w;
        ss += w.x * w.x + w.y * w.y + w.z * w.z + w.w * w.w;
    }
#pragma unroll
    for (int off = 1; off <= 32; off <<= 1) { s += __shfl_xor(s, off); ss += __shfl_xor(ss, off); }
    const float mean = s * (1.f / 768.f);
    float var = (ss - 768.f * mean * mean) * (1.f / 767.f);
    var = fmaxf(var, 0.f);
    const float inv = 1.f / (sqrtf(var) + 1e-6f);
#pragma unroll
    for (int j = 0; j < 3; ++j) {
        float4 gv = ((const float4*)g)[lane + 64 * j];
        float4 bv = ((const float4*)bt)[lane + 64 * j];
        float4 y;
        y.x = gv.x * (v[j].x - mean) * inv + bv.x;
        y.y = gv.y * (v[j].y - mean) * inv + bv.y;
        y.z = gv.z * (v[j].z - mean) * inv + bv.z;
        y.w = gv.w * (v[j].w - mean) * inv + bv.w;
        ((float4*)(outf + (size_t)row * 768))[lane + 64 * j] = y;
        if (MODE == 0) {
            bf16x4 o;
            o[0] = (bf16)y.x; o[1] = (bf16)y.y; o[2] = (bf16)y.z; o[3] = (bf16)y.w;
            ((bf16x4*)(outb + (size_t)row * 768))[lane + 64 * j] = o;
        }
    }
}

// ---------------- launcher ----------------

extern "C" void kernel_launch(void* const* d_in, const int* in_sizes, int n_in,
                              void* d_out, int out_size, void* d_ws, size_t ws_size,
                              hipStream_t stream) {
    const float* hidden = (const float*)d_in[0];
    const float* mask   = (const float*)d_in[1];
    const float* pb     = (const float*)d_in[2];
    const float* Wq = (const float*)d_in[3];
    const float* bq = (const float*)d_in[4];
    const float* Wk = (const float*)d_in[5];
    const float* bk = (const float*)d_in[6];
    const float* Wv = (const float*)d_in[7];
    const float* bv = (const float*)d_in[8];
    const float* Wo = (const float*)d_in[9];
    const float* bo = (const float*)d_in[10];
    const float* W1 = (const float*)d_in[11];
    const float* b1 = (const float*)d_in[12];
    const float* W2 = (const float*)d_in[13];
    const float* b2 = (const float*)d_in[14];
    const float* g1  = (const float*)d_in[15];
    const float* be1 = (const float*)d_in[16];
    const float* g2  = (const float*)d_in[17];
    const float* be2 = (const float*)d_in[18];
    float* out = (float*)d_out;

    char* ws = (char*)d_ws;
    bf16*  xbf     = (bf16*)(ws);                    // 12,582,912 B ; later reused as inter_bf
    bf16*  wqkv_t  = (bf16*)(ws + 12582912);         // 3,538,944
    bf16*  wo_t    = (bf16*)(ws + 16121856);         // 1,179,648
    bf16*  w1_t    = (bf16*)(ws + 17301504);         // 4,718,592
    bf16*  w2_t    = (bf16*)(ws + 22020096);         // 4,718,592
    float* bqkv    = (float*)(ws + 26738688);        // 9,216
    bf16*  qkv     = (bf16*)(ws + 26747904);         // region 50,331,648 (QKV then FFN1)
    bf16*  ffn1    = qkv;
    bf16*  ctx     = (bf16*)(ws + 77079552);         // 12,582,912
    float* attn_out= (float*)(ws + 89662464);        // 25,165,824 ; later reused as ffn2
    float* ffn2    = attn_out;
    float* interf  = (float*)(ws + 114828288);       // 25,165,824  (end 139,994,112)
    bf16*  interb  = xbf;

    cast_bf16_kernel<<<6291456 / 4 / 256, 256, 0, stream>>>(hidden, xbf, 6291456 / 4);
    tcast_kernel<<<dim3(24, 24), 256, 0, stream>>>(Wq, wqkv_t, 768, 768);
    tcast_kernel<<<dim3(24, 24), 256, 0, stream>>>(Wk, wqkv_t + 768 * 768, 768, 768);
    tcast_kernel<<<dim3(24, 24), 256, 0, stream>>>(Wv, wqkv_t + 2 * 768 * 768, 768, 768);
    tcast_kernel<<<dim3(24, 24), 256, 0, stream>>>(Wo, wo_t, 768, 768);
    tcast_kernel<<<dim3(96, 24), 256, 0, stream>>>(W1, w1_t, 768, 3072);
    tcast_kernel<<<dim3(24, 96), 256, 0, stream>>>(W2, w2_t, 3072, 768);
    concat_bias_kernel<<<9, 256, 0, stream>>>(bq, bk, bv, bqkv);

    gemm_kernel<0><<<dim3(18, 64), 256, 0, stream>>>(xbf, wqkv_t, bqkv, qkv, nullptr, 8192, 2304, 768, 2304);
    attn_kernel<<<dim3(64, 96), 256, 0, stream>>>(qkv, pb, mask, ctx);
    gemm_kernel<1><<<dim3(6, 64), 256, 0, stream>>>(ctx, wo_t, bo, nullptr, attn_out, 8192, 768, 768, 768);
    ln_kernel<0><<<2048, 256, 0, stream>>>(attn_out, hidden, g1, be1, interf, interb);
    gemm_kernel<2><<<dim3(24, 64), 256, 0, stream>>>(interb, w1_t, b1, ffn1, nullptr, 8192, 3072, 768, 3072);
    gemm_kernel<1><<<dim3(6, 64), 256, 0, stream>>>(ffn1, w2_t, b2, nullptr, ffn2, 8192, 768, 3072, 768);
    ln_kernel<1><<<2048, 256, 0, stream>>>(ffn2, interf, g2, be2, out, nullptr);
}